// Round 15
// baseline (111.973 us; speedup 1.0000x reference)
//
#include <hip/hip_runtime.h>
#include <stdint.h>

#define B 8
#define N 460800
#define NV4 115200          // N/4 float4 scores per image
#define PRE 2000
#define POST 1000
#define CAP 4096
#define NBIN 4096
#define RANKP 2048
#define NWORD 32
#define NMS_T 0.7f
#define XCLIP 4.135166556742356

#define SCAN_BLOCKS 45      // 45*256*10 = 115200
#define SCAN_ITER 10
#define SCAN_STRIDE (SCAN_BLOCKS * 256)

typedef unsigned long long u64;

__device__ __forceinline__ uint32_t fkey(float f) {
    uint32_t u = __float_as_uint(f);
    return (u & 0x80000000u) ? ~u : (u | 0x80000000u);
}

__device__ __forceinline__ u64 readlane_u64(u64 v, int lane) {
    uint32_t lo = __builtin_amdgcn_readlane((uint32_t)v, lane);
    uint32_t hi = __builtin_amdgcn_readlane((uint32_t)(v >> 32), lane);
    return ((u64)hi << 32) | lo;
}

// async global->LDS DMA, 16B per lane: dest = lds_base (uniform) + lane*16.
__device__ __forceinline__ void gload_lds16(const void* g, void* l) {
    __builtin_amdgcn_global_load_lds(
        (const __attribute__((address_space(1))) void*)g,
        (__attribute__((address_space(3))) void*)l, 16, 0, 0);
}

// LDS byte offset of a __shared__ pointer (AS3 ptrs are 32-bit offsets).
__device__ __forceinline__ uint32_t lds_addr(const void* p) {
    return (uint32_t)(uintptr_t)(const __attribute__((address_space(3))) void*)p;
}

// ---------------- Stage 1: per-image histogram of score keys (top 12 bits) ----------------
__global__ __launch_bounds__(256) void k_hist(const float4* __restrict__ obj4,
                                              uint32_t* __restrict__ hist) {
    __shared__ uint32_t lh[2][NBIN];   // 32 KiB, 2-way replicated to cut contention
    int b = blockIdx.y;
    for (int i = threadIdx.x; i < NBIN; i += 256) { lh[0][i] = 0; lh[1][i] = 0; }
    __syncthreads();
    const float4* s = obj4 + (size_t)b * NV4;
    int t0 = blockIdx.x * 256 + threadIdx.x;
    uint32_t* h = lh[threadIdx.x & 1];
    float4 v[SCAN_ITER];
#pragma unroll
    for (int k = 0; k < SCAN_ITER; ++k) v[k] = s[t0 + k * SCAN_STRIDE];
#pragma unroll
    for (int k = 0; k < SCAN_ITER; ++k) {
        atomicAdd(&h[fkey(v[k].x) >> 20], 1u);
        atomicAdd(&h[fkey(v[k].y) >> 20], 1u);
        atomicAdd(&h[fkey(v[k].z) >> 20], 1u);
        atomicAdd(&h[fkey(v[k].w) >> 20], 1u);
    }
    __syncthreads();
    uint32_t* gh = hist + (size_t)b * NBIN;
    for (int i = threadIdx.x; i < NBIN; i += 256) {
        uint32_t s2 = lh[0][i] + lh[1][i];
        if (s2) atomicAdd(&gh[i], s2);
    }
}

// ---------------- Stage 2+3 fused: wave 0 computes cutoff bin, then compact ------------
#define LBUF 2048
__global__ __launch_bounds__(256) void k_compact(const float4* __restrict__ obj4,
                                                 const uint32_t* __restrict__ hist,
                                                 uint32_t* __restrict__ cnt,
                                                 u64* __restrict__ cand) {
    __shared__ u64 buf[LBUF];          // 16 KiB
    __shared__ uint32_t lcnt, base, cutsh;
    int b = blockIdx.y;
    if (threadIdx.x == 0) lcnt = 0;
    if (threadIdx.x < 64) {
        int lane = threadIdx.x;
        const uint32_t* h = hist + (size_t)b * NBIN;
        uint32_t gs = 0;
        for (int t = 0; t < 64; ++t) gs += h[lane * 64 + t];
        uint32_t suf = gs;
        for (int d = 1; d < 64; d <<= 1) {
            uint32_t vv = __shfl_down(suf, d);
            if (lane + d < 64) suf += vv;
        }
        unsigned long long m = __ballot(suf >= PRE);
        int G = 63 - __clzll(m);
        uint32_t A = 0;
        if (G < 63) A = __shfl(suf, G + 1);
        uint32_t hv = h[G * 64 + lane];
        uint32_t suf2 = hv;
        for (int d = 1; d < 64; d <<= 1) {
            uint32_t vv = __shfl_down(suf2, d);
            if (lane + d < 64) suf2 += vv;
        }
        unsigned long long m2 = __ballot(A + suf2 >= PRE);
        int t2 = 63 - __clzll(m2);
        if (lane == 0) cutsh = (uint32_t)(G * 64 + t2);
    }
    __syncthreads();
    uint32_t cb = cutsh;
    const float4* s = obj4 + (size_t)b * NV4;
    int t0 = blockIdx.x * 256 + threadIdx.x;
    float4 v[SCAN_ITER];
#pragma unroll
    for (int k = 0; k < SCAN_ITER; ++k) v[k] = s[t0 + k * SCAN_STRIDE];
#pragma unroll
    for (int k = 0; k < SCAN_ITER; ++k) {
        int i4 = (t0 + k * SCAN_STRIDE) * 4;
        float fv[4] = {v[k].x, v[k].y, v[k].z, v[k].w};
#pragma unroll
        for (int c = 0; c < 4; ++c) {
            uint32_t key = fkey(fv[c]);
            if ((key >> 20) >= cb) {
                uint32_t p = atomicAdd(&lcnt, 1u);
                u64 e = ((u64)key << 32) | (uint32_t)(~(uint32_t)(i4 + c));
                if (p < LBUF) buf[p] = e;
                else {
                    uint32_t g = atomicAdd(&cnt[b], 1u);
                    if (g < CAP) cand[(size_t)b * CAP + g] = e;
                }
            }
        }
    }
    __syncthreads();
    uint32_t nb = lcnt < LBUF ? lcnt : LBUF;
    if (threadIdx.x == 0) base = atomicAdd(&cnt[b], nb);
    __syncthreads();
    uint32_t bs = base;
    for (uint32_t t = threadIdx.x; t < nb; t += 256) {
        uint32_t g = bs + t;
        if (g < CAP) cand[(size_t)b * CAP + g] = buf[t];
    }
}

// ---------------- Stage 4+5: counting-rank (readlane broadcast) + decode ----------------
__global__ __launch_bounds__(64) void k_rankdec(const uint32_t* __restrict__ cnt,
                                                const u64* __restrict__ cand,
                                                const float4* __restrict__ anchors,
                                                const float4* __restrict__ deltas,
                                                float4* __restrict__ boxes) {
    int b = blockIdx.x;
    int lane = threadIdx.x;                       // 64
    int slot = blockIdx.y * 64 + lane;            // 0..4095
    uint32_t n = cnt[b]; if (n > CAP) n = CAP;
    const u64* C = cand + (size_t)b * CAP;
    u64 mykey = (slot < (int)n) ? C[slot] : 0ull;
    int ng = ((int)n + 63) >> 6;
    auto ld = [&](int g) -> u64 {
        int j = g * 64 + lane;
        int jc = j < (CAP - 1) ? j : (CAP - 1);
        u64 kv = C[jc];
        return (j < (int)n) ? kv : 0ull;          // 0 never counts (real keys have MSB set)
    };
    u64 kv0 = ld(0), kv1 = ld(1), kv2 = ld(2);
    int r0 = 0, r1 = 0;
    for (int g = 0; g < ng; ++g) {
        u64 kvn = ld(g + 3);
#pragma unroll
        for (int t = 0; t < 64; t += 2) {
            u64 ka = readlane_u64(kv0, t);
            u64 kb = readlane_u64(kv0, t + 1);
            r0 += (ka > mykey) ? 1 : 0;
            r1 += (kb > mykey) ? 1 : 0;
        }
        kv0 = kv1; kv1 = kv2; kv2 = kvn;
    }
    int r = r0 + r1;
    int rank = (slot < (int)n) ? r : slot;        // pads cover rows [n,2048) bijectively
    if (rank < RANKP) {
        float4 outb = make_float4(0.f, 0.f, 0.f, 0.f);
        if (slot < (int)n && rank < PRE) {
            uint32_t idx = ~(uint32_t)mykey;
            if (idx < N) {
                float4 a = anchors[idx];
                float4 d = deltas[(size_t)b * N + idx];
                float w = a.z - a.x, h = a.w - a.y;
                float cx = a.x + 0.5f * w, cy = a.y + 0.5f * h;
                float dw = fminf(d.z, (float)XCLIP);
                float dh = fminf(d.w, (float)XCLIP);
                float pcx = d.x * w + cx, pcy = d.y * h + cy;
                float pw = expf(dw) * w, ph = expf(dh) * h;
                float x1 = pcx - 0.5f * pw, y1 = pcy - 0.5f * ph;
                float x2 = pcx + 0.5f * pw, y2 = pcy + 0.5f * ph;
                x1 = fminf(fmaxf(x1, 0.f), 1024.f);
                y1 = fminf(fmaxf(y1, 0.f), 1024.f);
                x2 = fminf(fmaxf(x2, 0.f), 1024.f);
                y2 = fminf(fmaxf(y2, 0.f), 1024.f);
                outb = make_float4(x1, y1, x2, y2);
            }
        }
        boxes[(size_t)b * RANKP + rank] = outb;
    }
}

// ---------------- Stage 6a: pairwise suppression bitmask + diag + valid ----------------
#define NTRI (NWORD * (NWORD + 1) / 2)   // 528
__global__ void k_mask(const float4* __restrict__ boxes, u64* __restrict__ sup,
                       u64* __restrict__ diagd, u64* __restrict__ valid) {
    int b = blockIdx.x;
    int L = blockIdx.y;
    int ti = 0, rem = L;
    while (rem >= NWORD - ti) { rem -= NWORD - ti; ++ti; }
    int tj = ti + rem;
    __shared__ float4 jb[64];
    __shared__ float ja[64];
    int t = threadIdx.x;  // 64 threads
    const float4* bx = boxes + (size_t)b * RANKP;
    float4 v = bx[tj * 64 + t];
    jb[t] = v;
    ja[t] = (v.z - v.x) * (v.w - v.y);
    int i = ti * 64 + t;
    float4 bi = bx[i];
    float ai = (bi.z - bi.x) * (bi.w - bi.y);
    __syncthreads();
    u64 word = 0;
    for (int jj = 0; jj < 64; ++jj) {
        int j = tj * 64 + jj;
        float4 bj = jb[jj];
        float xx1 = fmaxf(bi.x, bj.x), yy1 = fmaxf(bi.y, bj.y);
        float xx2 = fminf(bi.z, bj.z), yy2 = fminf(bi.w, bj.w);
        float iw = fmaxf(xx2 - xx1, 0.f), ih = fmaxf(yy2 - yy1, 0.f);
        float inter = iw * ih;
        float iou = inter / (ai + ja[jj] - inter);
        if (j > i && iou > NMS_T) word |= 1ull << jj;
    }
    sup[((size_t)b * RANKP + i) * NWORD + tj] = word;
    if (ti == tj) {
        diagd[((size_t)b * NWORD + ti) * 64 + t] = word;
        bool ok = !((bi.z - bi.x < 1e-3f) || (bi.w - bi.y < 1e-3f));
        u64 bal = __ballot(ok);
        if (t == 0) valid[(size_t)b * NWORD + ti] = bal;
    }
}

// ---------------- Stage 6b+7: producer/consumer wave-specialized greedy NMS ----------------
// Wave 0 (producer): ONLY issues global_load_lds into a 4-slot LDS ring, counted
// vmcnt(32), raw s_barrier per chunk. Its single LDS read (exit flag) is inline-asm
// ds_read_b32 so the compiler cannot attach a conservative vmcnt(0) drain to it.
// Wave 1 (consumer): serial NMS chain reading PLAIN C++ LDS — its path has zero
// outstanding VMEM, so compiler-inserted waits are free (waitcnt insertion is
// path-sensitive). Raw s_barrier (NOT __syncthreads — that drains the DMA queue).
// Producer stays 2 chunks ahead (~2 chunk-times of latency cover).
// Barrier count is matched on both paths incl. early exit — do not alter one side only.
// sup lower-triangle words (w < row's chunk) are NEVER written (0xAA poison from the
// harness) — the `lane >= c` guard keeps them out of remv. Do not remove it.
__global__ __launch_bounds__(128, 1) void k_nms(const u64* __restrict__ valid,
                                                const u64* __restrict__ sup,
                                                const u64* __restrict__ diagd,
                                                const float4* __restrict__ boxes,
                                                float4* __restrict__ out) {
    __shared__ u64 Dg[NWORD * 64];      // 16 KiB: all 32 diagonal tiles
    __shared__ u64 Bf[4][64 * NWORD];   // 4 x 16 KiB chunk ring
    __shared__ int dflag;               // early-exit flag
    int b = blockIdx.x;
    int tid = threadIdx.x;
    int wid = tid >> 6;                 // 0 = producer, 1 = consumer
    int lane = tid & 63;
    int w = lane & 31, hh = lane >> 5;
    const u64* S = sup + (size_t)b * RANKP * NWORD;

    if (wid == 0) {
        // ======== producer wave ========
        if (lane == 0) dflag = 0;
        const char* gd = (const char*)(diagd + (size_t)b * (NWORD * 64));
#pragma unroll
        for (int i = 0; i < 16; ++i)
            gload_lds16(gd + i * 1024 + lane * 16, (char*)Dg + i * 1024);
        {
            const char* g0 = (const char*)S;
#pragma unroll
            for (int i = 0; i < 16; ++i)
                gload_lds16(g0 + i * 1024 + lane * 16, (char*)&Bf[0][0] + i * 1024);
        }
        asm volatile("s_waitcnt vmcnt(0) lgkmcnt(0)" ::: "memory");  // Dg+c0 done, flag=0 done
        // issue chunks 1,2 (stay in flight across the barrier)
#pragma unroll
        for (int t = 1; t < 3; ++t) {
            const char* gn = (const char*)(S + (size_t)t * 64 * NWORD);
            char* lb = (char*)&Bf[t][0];
#pragma unroll
            for (int i = 0; i < 16; ++i)
                gload_lds16(gn + i * 1024 + lane * 16, lb + i * 1024);
        }
        __builtin_amdgcn_s_barrier();           // #1: chunk 0 ready
        uint32_t fa = lds_addr(&dflag);
        for (int c = 0; c < NWORD; ++c) {
            int cn = (c + 3) & (NWORD - 1);     // wrapped issues never read; counts fixed
            const char* gn = (const char*)(S + (size_t)cn * 64 * NWORD);
            char* lb = (char*)&Bf[(c + 3) & 3][0];
#pragma unroll
            for (int i = 0; i < 16; ++i)
                gload_lds16(gn + i * 1024 + lane * 16, lb + i * 1024);
            asm volatile("s_waitcnt vmcnt(32)" ::: "memory");   // chunk c+1 complete
            __builtin_amdgcn_s_barrier();       // #c+2: chunk c+1 ready / slot free
            int df;
            asm volatile("ds_read_b32 %0, %1\n\ts_waitcnt lgkmcnt(0)"
                         : "=v"(df) : "v"(fa) : "memory");
            if (df) break;                      // uniform
        }
    } else {
        // ======== consumer wave ========
        u64 remv = (lane < 32) ? ~valid[(size_t)b * NWORD + lane] : 0ull;
        int kept_cnt = 0;
        __builtin_amdgcn_s_barrier();           // #1: chunk 0 ready
        for (int c = 0; c < NWORD; ++c) {
            __builtin_amdgcn_sched_barrier(0);
            // ---- step1: serial scalar recurrence on diagonal tile ----
            u64 dcur = Dg[(c << 6) + lane];
            u64 scur = readlane_u64(remv, c);
#pragma unroll
            for (int g = 0; g < 4; ++g) {
                u64 dd[16];
#pragma unroll
                for (int i = 0; i < 16; ++i) dd[i] = readlane_u64(dcur, g * 16 + i);
#pragma unroll
                for (int i = 0; i < 16; ++i) {
                    int row = g * 16 + i;
                    if (!((scur >> row) & 1ull)) scur |= dd[i];
                }
            }
            u64 kept = ~scur;
            // ---- step2: OR kept rows into remv (plain LDS reads; no VMEM on this path) ----
            uint32_t kk = hh ? (uint32_t)(kept >> 32) : (uint32_t)kept;
            const u64* bf = &Bf[c & 3][0];
            u64 acc = 0;
#pragma unroll
            for (int r = 0; r < 32; ++r) {
                u64 m = (u64)(int64_t)((int32_t)(kk << (31 - r)) >> 31);  // replicate bit r
                acc |= bf[(hh * 32 + r) * NWORD + w] & m;
            }
            u64 acco = __shfl(acc, lane + 32);
            if (lane < 32 && lane >= c) remv |= (acc | acco);
            kept_cnt += (int)__popcll(kept);
            bool fin = (kept_cnt >= POST);      // uniform (scalar-chain value)
            if (fin && lane == 0) dflag = 1;
            asm volatile("s_waitcnt lgkmcnt(0)" ::: "memory");  // flag + reads retired
            __builtin_amdgcn_s_barrier();       // #c+2
            if (fin) break;
        }
        // ---- epilogue: stable partition (kept first) -> top-1000 gather ----
        int tot = 0;
        for (int ww = 0; ww < NWORD; ++ww)
            tot += (int)__popcll(~readlane_u64(remv, ww));
        u64 below = (1ull << lane) - 1ull;
        int kcum = 0, ucum = 0;
        for (int ww = 0; ww < NWORD; ++ww) {
            u64 kw = ~readlane_u64(remv, ww);
            int pc = (int)__popcll(kw);
            bool kp = (kw >> lane) & 1ull;
            int pos;
            if (kp) pos = kcum + (int)__popcll(kw & below);
            else    pos = tot + ucum + (int)__popcll((~kw) & below);
            if (pos < POST) out[(size_t)b * POST + pos] = boxes[(size_t)b * RANKP + ww * 64 + lane];
            kcum += pc;
            ucum += 64 - pc;
        }
    }
}

extern "C" void kernel_launch(void* const* d_in, const int* in_sizes, int n_in,
                              void* d_out, int out_size, void* d_ws, size_t ws_size,
                              hipStream_t stream) {
    const float* anchors = (const float*)d_in[0];   // [N,4]
    const float* obj     = (const float*)d_in[1];   // [B,N]
    const float* deltas  = (const float*)d_in[2];   // [B,N,4]
    char* ws = (char*)d_ws;

    uint32_t* hist   = (uint32_t*)(ws + 0);        // 131072
    uint32_t* cnt    = (uint32_t*)(ws + 131072);   // 256
    u64*      cand   = (u64*)(ws + 131584);        // B*4096*8 = 262144 -> 393728
    float4*   boxes  = (float4*)(ws + 393728);     // B*2048*16 = 524288 -> 918016
    u64*      valid  = (u64*)(ws + 918016);        // 2048 -> 920064
    u64*      sup    = (u64*)(ws + 920064);        // B*2048*32*8 = 4194304 -> 5114368
    u64*      diagd  = (u64*)(ws + 5114368);       // B*32*64*8 = 131072 -> 5245440

    hipMemsetAsync(ws, 0, 131328, stream);  // hist + cnt

    dim3 gscan(SCAN_BLOCKS, B);
    k_hist<<<gscan, 256, 0, stream>>>((const float4*)obj, hist);
    k_compact<<<gscan, 256, 0, stream>>>((const float4*)obj, hist, cnt, cand);
    dim3 grank(B, CAP / 64);
    k_rankdec<<<grank, 64, 0, stream>>>(cnt, cand, (const float4*)anchors,
                                        (const float4*)deltas, boxes);
    dim3 gmask(B, NTRI);
    k_mask<<<gmask, 64, 0, stream>>>(boxes, sup, diagd, valid);
    k_nms<<<B, 128, 0, stream>>>(valid, sup, diagd, boxes, (float4*)d_out);
}

// Round 17
// 107.984 us; speedup vs baseline: 1.0369x; 1.0369x over previous
//
#include <hip/hip_runtime.h>
#include <stdint.h>

#define B 8
#define N 460800
#define NV4 115200          // N/4 float4 scores per image
#define PRE 2000
#define POST 1000
#define CAP 4096
#define NBIN 4096
#define RANKP 2048
#define NWORD 32
#define NMS_T 0.7f
#define XCLIP 4.135166556742356

#define SCAN_BLOCKS 45      // 45*256*10 = 115200
#define SCAN_ITER 10
#define SCAN_STRIDE (SCAN_BLOCKS * 256)

typedef unsigned long long u64;

__device__ __forceinline__ uint32_t fkey(float f) {
    uint32_t u = __float_as_uint(f);
    return (u & 0x80000000u) ? ~u : (u | 0x80000000u);
}

__device__ __forceinline__ u64 readlane_u64(u64 v, int lane) {
    uint32_t lo = __builtin_amdgcn_readlane((uint32_t)v, lane);
    uint32_t hi = __builtin_amdgcn_readlane((uint32_t)(v >> 32), lane);
    return ((u64)hi << 32) | lo;
}

// ---------------- Stage 1: per-image histogram of score keys (top 12 bits) ----------------
__global__ __launch_bounds__(256) void k_hist(const float4* __restrict__ obj4,
                                              uint32_t* __restrict__ hist) {
    __shared__ uint32_t lh[2][NBIN];   // 32 KiB, 2-way replicated to cut contention
    int b = blockIdx.y;
    for (int i = threadIdx.x; i < NBIN; i += 256) { lh[0][i] = 0; lh[1][i] = 0; }
    __syncthreads();
    const float4* s = obj4 + (size_t)b * NV4;
    int t0 = blockIdx.x * 256 + threadIdx.x;
    uint32_t* h = lh[threadIdx.x & 1];
    float4 v[SCAN_ITER];
#pragma unroll
    for (int k = 0; k < SCAN_ITER; ++k) v[k] = s[t0 + k * SCAN_STRIDE];
#pragma unroll
    for (int k = 0; k < SCAN_ITER; ++k) {
        atomicAdd(&h[fkey(v[k].x) >> 20], 1u);
        atomicAdd(&h[fkey(v[k].y) >> 20], 1u);
        atomicAdd(&h[fkey(v[k].z) >> 20], 1u);
        atomicAdd(&h[fkey(v[k].w) >> 20], 1u);
    }
    __syncthreads();
    uint32_t* gh = hist + (size_t)b * NBIN;
    for (int i = threadIdx.x; i < NBIN; i += 256) {
        uint32_t s2 = lh[0][i] + lh[1][i];
        if (s2) atomicAdd(&gh[i], s2);
    }
}

// ---------------- Stage 2+3 fused: wave 0 computes cutoff bin, then compact ------------
#define LBUF 2048
__global__ __launch_bounds__(256) void k_compact(const float4* __restrict__ obj4,
                                                 const uint32_t* __restrict__ hist,
                                                 uint32_t* __restrict__ cnt,
                                                 u64* __restrict__ cand) {
    __shared__ u64 buf[LBUF];          // 16 KiB
    __shared__ uint32_t lcnt, base, cutsh;
    int b = blockIdx.y;
    if (threadIdx.x == 0) lcnt = 0;
    if (threadIdx.x < 64) {
        int lane = threadIdx.x;
        const uint32_t* h = hist + (size_t)b * NBIN;
        uint32_t gs = 0;
        for (int t = 0; t < 64; ++t) gs += h[lane * 64 + t];
        uint32_t suf = gs;
        for (int d = 1; d < 64; d <<= 1) {
            uint32_t vv = __shfl_down(suf, d);
            if (lane + d < 64) suf += vv;
        }
        unsigned long long m = __ballot(suf >= PRE);
        int G = 63 - __clzll(m);
        uint32_t A = 0;
        if (G < 63) A = __shfl(suf, G + 1);
        uint32_t hv = h[G * 64 + lane];
        uint32_t suf2 = hv;
        for (int d = 1; d < 64; d <<= 1) {
            uint32_t vv = __shfl_down(suf2, d);
            if (lane + d < 64) suf2 += vv;
        }
        unsigned long long m2 = __ballot(A + suf2 >= PRE);
        int t2 = 63 - __clzll(m2);
        if (lane == 0) cutsh = (uint32_t)(G * 64 + t2);
    }
    __syncthreads();
    uint32_t cb = cutsh;
    const float4* s = obj4 + (size_t)b * NV4;
    int t0 = blockIdx.x * 256 + threadIdx.x;
    float4 v[SCAN_ITER];
#pragma unroll
    for (int k = 0; k < SCAN_ITER; ++k) v[k] = s[t0 + k * SCAN_STRIDE];
#pragma unroll
    for (int k = 0; k < SCAN_ITER; ++k) {
        int i4 = (t0 + k * SCAN_STRIDE) * 4;
        float fv[4] = {v[k].x, v[k].y, v[k].z, v[k].w};
#pragma unroll
        for (int c = 0; c < 4; ++c) {
            uint32_t key = fkey(fv[c]);
            if ((key >> 20) >= cb) {
                uint32_t p = atomicAdd(&lcnt, 1u);
                u64 e = ((u64)key << 32) | (uint32_t)(~(uint32_t)(i4 + c));
                if (p < LBUF) buf[p] = e;
                else {
                    uint32_t g = atomicAdd(&cnt[b], 1u);
                    if (g < CAP) cand[(size_t)b * CAP + g] = e;
                }
            }
        }
    }
    __syncthreads();
    uint32_t nb = lcnt < LBUF ? lcnt : LBUF;
    if (threadIdx.x == 0) base = atomicAdd(&cnt[b], nb);
    __syncthreads();
    uint32_t bs = base;
    for (uint32_t t = threadIdx.x; t < nb; t += 256) {
        uint32_t g = bs + t;
        if (g < CAP) cand[(size_t)b * CAP + g] = buf[t];
    }
}

// ---------------- Stage 4+5: counting-rank (readlane broadcast) + decode ----------------
__global__ __launch_bounds__(64) void k_rankdec(const uint32_t* __restrict__ cnt,
                                                const u64* __restrict__ cand,
                                                const float4* __restrict__ anchors,
                                                const float4* __restrict__ deltas,
                                                float4* __restrict__ boxes) {
    int b = blockIdx.x;
    int lane = threadIdx.x;                       // 64
    int slot = blockIdx.y * 64 + lane;            // 0..4095
    uint32_t n = cnt[b]; if (n > CAP) n = CAP;
    const u64* C = cand + (size_t)b * CAP;
    u64 mykey = (slot < (int)n) ? C[slot] : 0ull;
    int ng = ((int)n + 63) >> 6;
    auto ld = [&](int g) -> u64 {
        int j = g * 64 + lane;
        int jc = j < (CAP - 1) ? j : (CAP - 1);
        u64 kv = C[jc];
        return (j < (int)n) ? kv : 0ull;          // 0 never counts (real keys have MSB set)
    };
    u64 kv0 = ld(0), kv1 = ld(1), kv2 = ld(2);
    int r0 = 0, r1 = 0;
    for (int g = 0; g < ng; ++g) {
        u64 kvn = ld(g + 3);
#pragma unroll
        for (int t = 0; t < 64; t += 2) {
            u64 ka = readlane_u64(kv0, t);
            u64 kb = readlane_u64(kv0, t + 1);
            r0 += (ka > mykey) ? 1 : 0;
            r1 += (kb > mykey) ? 1 : 0;
        }
        kv0 = kv1; kv1 = kv2; kv2 = kvn;
    }
    int r = r0 + r1;
    int rank = (slot < (int)n) ? r : slot;        // pads cover rows [n,2048) bijectively
    if (rank < RANKP) {
        float4 outb = make_float4(0.f, 0.f, 0.f, 0.f);
        if (slot < (int)n && rank < PRE) {
            uint32_t idx = ~(uint32_t)mykey;
            if (idx < N) {
                float4 a = anchors[idx];
                float4 d = deltas[(size_t)b * N + idx];
                float w = a.z - a.x, h = a.w - a.y;
                float cx = a.x + 0.5f * w, cy = a.y + 0.5f * h;
                float dw = fminf(d.z, (float)XCLIP);
                float dh = fminf(d.w, (float)XCLIP);
                float pcx = d.x * w + cx, pcy = d.y * h + cy;
                float pw = expf(dw) * w, ph = expf(dh) * h;
                float x1 = pcx - 0.5f * pw, y1 = pcy - 0.5f * ph;
                float x2 = pcx + 0.5f * pw, y2 = pcy + 0.5f * ph;
                x1 = fminf(fmaxf(x1, 0.f), 1024.f);
                y1 = fminf(fmaxf(y1, 0.f), 1024.f);
                x2 = fminf(fmaxf(x2, 0.f), 1024.f);
                y2 = fminf(fmaxf(y2, 0.f), 1024.f);
                outb = make_float4(x1, y1, x2, y2);
            }
        }
        boxes[(size_t)b * RANKP + rank] = outb;
    }
}

// ---------------- Stage 6a: pairwise suppression bitmask + diag + valid ----------------
// sup/diagd stored NONTEMPORAL (nt): keeps the lines out of the writer XCD's L2 so
// k_nms's reads stream from L3/HBM instead of paying cross-XCD dirty-line service.
#define NTRI (NWORD * (NWORD + 1) / 2)   // 528
__global__ void k_mask(const float4* __restrict__ boxes, u64* __restrict__ sup,
                       u64* __restrict__ diagd, u64* __restrict__ valid) {
    int b = blockIdx.x;
    int L = blockIdx.y;
    int ti = 0, rem = L;
    while (rem >= NWORD - ti) { rem -= NWORD - ti; ++ti; }
    int tj = ti + rem;
    __shared__ float4 jb[64];
    __shared__ float ja[64];
    int t = threadIdx.x;  // 64 threads
    const float4* bx = boxes + (size_t)b * RANKP;
    float4 v = bx[tj * 64 + t];
    jb[t] = v;
    ja[t] = (v.z - v.x) * (v.w - v.y);
    int i = ti * 64 + t;
    float4 bi = bx[i];
    float ai = (bi.z - bi.x) * (bi.w - bi.y);
    __syncthreads();
    u64 word = 0;
    for (int jj = 0; jj < 64; ++jj) {
        int j = tj * 64 + jj;
        float4 bj = jb[jj];
        float xx1 = fmaxf(bi.x, bj.x), yy1 = fmaxf(bi.y, bj.y);
        float xx2 = fminf(bi.z, bj.z), yy2 = fminf(bi.w, bj.w);
        float iw = fmaxf(xx2 - xx1, 0.f), ih = fmaxf(yy2 - yy1, 0.f);
        float inter = iw * ih;
        float iou = inter / (ai + ja[jj] - inter);
        if (j > i && iou > NMS_T) word |= 1ull << jj;
    }
    __builtin_nontemporal_store(word, &sup[((size_t)b * RANKP + i) * NWORD + tj]);
    if (ti == tj) {
        __builtin_nontemporal_store(word, &diagd[((size_t)b * NWORD + ti) * 64 + t]);
        bool ok = !((bi.z - bi.x < 1e-3f) || (bi.w - bi.y < 1e-3f));
        u64 bal = __ballot(ok);
        if (t == 0) valid[(size_t)b * NWORD + ti] = bal;
    }
}

// ---------------- Stage 6b+7: chunked greedy NMS, pure-register asm pipeline ----------------
// (r14 version, verbatim — last known-good.) NO LDS, NO SMEM: rows (32 u64) + diag word
// per chunk live in named registers, loaded by inline-asm global_load_dwordx2 (A/B double
// buffer). Unroll-2 loop: issue next batch -> sched_barrier(0) -> compute current ->
// vmcnt(0)+sched_barrier. The sched_barrier(0) AFTER each ISSUE_ROWS tries to keep the
// compute below the issue (see r13 post-mortem).
// sup lower-triangle words (w < row's chunk) are NEVER written (0xAA poison from the
// harness) — the `lane >= c` guard keeps them out of remv. Do not remove it.
#define QLIST(X) X(0) X(1) X(2) X(3) X(4) X(5) X(6) X(7) X(8) X(9) X(10) X(11) \
    X(12) X(13) X(14) X(15) X(16) X(17) X(18) X(19) X(20) X(21) X(22) X(23)    \
    X(24) X(25) X(26) X(27) X(28) X(29) X(30) X(31)

#define DECLA(i) u64 A##i;
#define DECLB(i) u64 B##i;
#define ACCA(i) { u64 m_ = (u64)(int64_t)((int32_t)(kk << (31 - i)) >> 31); acc |= A##i & m_; }
#define ACCB(i) { u64 m_ = (u64)(int64_t)((int32_t)(kk << (31 - i)) >> 31); acc |= B##i & m_; }

#define ISSUE_ROWS(P, CC) do {                                                        \
    const char* g1_ = (const char*)S + ((size_t)((CC) & (NWORD - 1)) << 14);          \
    const char* g2_ = g1_ + 4096;                                                     \
    const char* gd_ = (const char*)Dv + ((size_t)((CC) & (NWORD - 1)) << 9);          \
    asm volatile(                                                                     \
        "global_load_dwordx2 %[q0], %[vo], %[sp] offset:0\n\t"                        \
        "global_load_dwordx2 %[q1], %[vo], %[sp] offset:256\n\t"                      \
        "global_load_dwordx2 %[q2], %[vo], %[sp] offset:512\n\t"                      \
        "global_load_dwordx2 %[q3], %[vo], %[sp] offset:768\n\t"                      \
        "global_load_dwordx2 %[q4], %[vo], %[sp] offset:1024\n\t"                     \
        "global_load_dwordx2 %[q5], %[vo], %[sp] offset:1280\n\t"                     \
        "global_load_dwordx2 %[q6], %[vo], %[sp] offset:1536\n\t"                     \
        "global_load_dwordx2 %[q7], %[vo], %[sp] offset:1792\n\t"                     \
        "global_load_dwordx2 %[q8], %[vo], %[sp] offset:2048\n\t"                     \
        "global_load_dwordx2 %[q9], %[vo], %[sp] offset:2304\n\t"                     \
        "global_load_dwordx2 %[q10], %[vo], %[sp] offset:2560\n\t"                    \
        "global_load_dwordx2 %[q11], %[vo], %[sp] offset:2816\n\t"                    \
        "global_load_dwordx2 %[q12], %[vo], %[sp] offset:3072\n\t"                    \
        "global_load_dwordx2 %[q13], %[vo], %[sp] offset:3328\n\t"                    \
        "global_load_dwordx2 %[q14], %[vo], %[sp] offset:3584\n\t"                    \
        "global_load_dwordx2 %[q15], %[vo], %[sp] offset:3840\n\t"                    \
        : [q0]"=&v"(P##0), [q1]"=&v"(P##1), [q2]"=&v"(P##2), [q3]"=&v"(P##3),         \
          [q4]"=&v"(P##4), [q5]"=&v"(P##5), [q6]"=&v"(P##6), [q7]"=&v"(P##7),         \
          [q8]"=&v"(P##8), [q9]"=&v"(P##9), [q10]"=&v"(P##10), [q11]"=&v"(P##11),     \
          [q12]"=&v"(P##12), [q13]"=&v"(P##13), [q14]"=&v"(P##14), [q15]"=&v"(P##15)  \
        : [vo]"v"(voff), [sp]"s"(g1_));                                               \
    asm volatile(                                                                     \
        "global_load_dwordx2 %[q16], %[vo], %[sp] offset:0\n\t"                       \
        "global_load_dwordx2 %[q17], %[vo], %[sp] offset:256\n\t"                     \
        "global_load_dwordx2 %[q18], %[vo], %[sp] offset:512\n\t"                     \
        "global_load_dwordx2 %[q19], %[vo], %[sp] offset:768\n\t"                     \
        "global_load_dwordx2 %[q20], %[vo], %[sp] offset:1024\n\t"                    \
        "global_load_dwordx2 %[q21], %[vo], %[sp] offset:1280\n\t"                    \
        "global_load_dwordx2 %[q22], %[vo], %[sp] offset:1536\n\t"                    \
        "global_load_dwordx2 %[q23], %[vo], %[sp] offset:1792\n\t"                    \
        "global_load_dwordx2 %[q24], %[vo], %[sp] offset:2048\n\t"                    \
        "global_load_dwordx2 %[q25], %[vo], %[sp] offset:2304\n\t"                    \
        "global_load_dwordx2 %[q26], %[vo], %[sp] offset:2560\n\t"                    \
        "global_load_dwordx2 %[q27], %[vo], %[sp] offset:2816\n\t"                    \
        "global_load_dwordx2 %[q28], %[vo], %[sp] offset:3072\n\t"                    \
        "global_load_dwordx2 %[q29], %[vo], %[sp] offset:3328\n\t"                    \
        "global_load_dwordx2 %[q30], %[vo], %[sp] offset:3584\n\t"                    \
        "global_load_dwordx2 %[q31], %[vo], %[sp] offset:3840\n\t"                    \
        "global_load_dwordx2 %[qd], %[vd], %[sd] offset:0\n\t"                        \
        : [q16]"=&v"(P##16), [q17]"=&v"(P##17), [q18]"=&v"(P##18), [q19]"=&v"(P##19), \
          [q20]"=&v"(P##20), [q21]"=&v"(P##21), [q22]"=&v"(P##22), [q23]"=&v"(P##23), \
          [q24]"=&v"(P##24), [q25]"=&v"(P##25), [q26]"=&v"(P##26), [q27]"=&v"(P##27), \
          [q28]"=&v"(P##28), [q29]"=&v"(P##29), [q30]"=&v"(P##30), [q31]"=&v"(P##31), \
          [qd]"=&v"(P##d)                                                             \
        : [vo]"v"(voff), [sp]"s"(g2_), [vd]"v"(vdiag), [sd]"s"(gd_));                 \
    __builtin_amdgcn_sched_barrier(0);  /* pin: compute must NOT hoist above issue */ \
} while (0)

#define WAITV0() do { asm volatile("s_waitcnt vmcnt(0)" ::: "memory");                \
                      __builtin_amdgcn_sched_barrier(0); } while (0)

#define NMS_BODY(ACCM, DREG, CC) do {                                                 \
    int cc_ = (CC);                                                                   \
    u64 dcur_ = (DREG);                                                               \
    u64 scur = readlane_u64(remv, cc_);                                               \
    _Pragma("unroll") for (int g = 0; g < 4; ++g) {                                   \
        u64 dd[16];                                                                   \
        _Pragma("unroll") for (int i = 0; i < 16; ++i)                                \
            dd[i] = readlane_u64(dcur_, g * 16 + i);                                  \
        _Pragma("unroll") for (int i = 0; i < 16; ++i) {                              \
            int row = g * 16 + i;                                                     \
            if (!((scur >> row) & 1ull)) scur |= dd[i];                               \
        }                                                                             \
    }                                                                                 \
    u64 kept = ~scur;                                                                 \
    uint32_t kk = hh ? (uint32_t)(kept >> 32) : (uint32_t)kept;                       \
    u64 acc = 0;                                                                      \
    QLIST(ACCM)                                                                       \
    u64 acco = __shfl(acc, lane + 32);                                                \
    if (lane < 32 && lane >= cc_) remv |= (acc | acco);                               \
    kept_cnt += (int)__popcll(kept);                                                  \
} while (0)

__global__ __launch_bounds__(64, 1) void k_nms(const u64* __restrict__ valid,
                                               const u64* __restrict__ sup,
                                               const u64* __restrict__ diagd,
                                               const float4* __restrict__ boxes,
                                               float4* __restrict__ out) {
    int b = blockIdx.x;
    int lane = threadIdx.x;             // 64
    int w = lane & 31, hh = lane >> 5;
    const u64* S = sup + (size_t)b * RANKP * NWORD;
    const u64* Dv = diagd + (size_t)b * (NWORD * 64);
    uint32_t voff  = (uint32_t)(hh * 8192 + w * 8);   // rows hh*32..hh*32+15 via imm
    uint32_t vdiag = (uint32_t)(lane * 8);
    u64 remv = (lane < 32) ? ~valid[(size_t)b * NWORD + lane] : 0ull;
    QLIST(DECLA) u64 Ad;
    QLIST(DECLB) u64 Bd;
    int kept_cnt = 0;
    ISSUE_ROWS(A, 0);
    WAITV0();
    for (int c = 0; c < NWORD; c += 2) {
        ISSUE_ROWS(B, c + 1);
        NMS_BODY(ACCA, Ad, c);
        if (kept_cnt >= POST) goto done;
        WAITV0();
        ISSUE_ROWS(A, c + 2);
        NMS_BODY(ACCB, Bd, c + 1);
        if (kept_cnt >= POST) goto done;
        WAITV0();
    }
done: ;
    // ---- epilogue: stable partition (kept first) -> top-1000 gather ----
    int tot = 0;
    for (int ww = 0; ww < NWORD; ++ww)
        tot += (int)__popcll(~readlane_u64(remv, ww));
    u64 below = (1ull << lane) - 1ull;
    int kcum = 0, ucum = 0;
    for (int ww = 0; ww < NWORD; ++ww) {
        u64 kw = ~readlane_u64(remv, ww);
        int pc = (int)__popcll(kw);
        bool kp = (kw >> lane) & 1ull;
        int pos;
        if (kp) pos = kcum + (int)__popcll(kw & below);
        else    pos = tot + ucum + (int)__popcll((~kw) & below);
        if (pos < POST) out[(size_t)b * POST + pos] = boxes[(size_t)b * RANKP + ww * 64 + lane];
        kcum += pc;
        ucum += 64 - pc;
    }
}

extern "C" void kernel_launch(void* const* d_in, const int* in_sizes, int n_in,
                              void* d_out, int out_size, void* d_ws, size_t ws_size,
                              hipStream_t stream) {
    const float* anchors = (const float*)d_in[0];   // [N,4]
    const float* obj     = (const float*)d_in[1];   // [B,N]
    const float* deltas  = (const float*)d_in[2];   // [B,N,4]
    char* ws = (char*)d_ws;

    uint32_t* hist   = (uint32_t*)(ws + 0);        // 131072
    uint32_t* cnt    = (uint32_t*)(ws + 131072);   // 256
    u64*      cand   = (u64*)(ws + 131584);        // B*4096*8 = 262144 -> 393728
    float4*   boxes  = (float4*)(ws + 393728);     // B*2048*16 = 524288 -> 918016
    u64*      valid  = (u64*)(ws + 918016);        // 2048 -> 920064
    u64*      sup    = (u64*)(ws + 920064);        // B*2048*32*8 = 4194304 -> 5114368
    u64*      diagd  = (u64*)(ws + 5114368);       // B*32*64*8 = 131072 -> 5245440

    hipMemsetAsync(ws, 0, 131328, stream);  // hist + cnt

    dim3 gscan(SCAN_BLOCKS, B);
    k_hist<<<gscan, 256, 0, stream>>>((const float4*)obj, hist);
    k_compact<<<gscan, 256, 0, stream>>>((const float4*)obj, hist, cnt, cand);
    dim3 grank(B, CAP / 64);
    k_rankdec<<<grank, 64, 0, stream>>>(cnt, cand, (const float4*)anchors,
                                        (const float4*)deltas, boxes);
    dim3 gmask(B, NTRI);
    k_mask<<<gmask, 64, 0, stream>>>(boxes, sup, diagd, valid);
    k_nms<<<B, 64, 0, stream>>>(valid, sup, diagd, boxes, (float4*)d_out);
}

// Round 18
// 106.345 us; speedup vs baseline: 1.0529x; 1.0154x over previous
//
#include <hip/hip_runtime.h>
#include <stdint.h>

#define B 8
#define N 460800
#define NV4 115200          // N/4 float4 scores per image
#define PRE 2000
#define POST 1000
#define CAP 4096
#define NBIN 4096
#define RANKP 2048
#define NWORD 32
#define NMS_T 0.7f
#define XCLIP 4.135166556742356

#define SCAN_BLOCKS 45      // 45*256*10 = 115200
#define SCAN_ITER 10
#define SCAN_STRIDE (SCAN_BLOCKS * 256)

typedef unsigned long long u64;
typedef uint32_t u32x4 __attribute__((ext_vector_type(4)));

__device__ __forceinline__ uint32_t fkey(float f) {
    uint32_t u = __float_as_uint(f);
    return (u & 0x80000000u) ? ~u : (u | 0x80000000u);
}

__device__ __forceinline__ u64 readlane_u64(u64 v, int lane) {
    uint32_t lo = __builtin_amdgcn_readlane((uint32_t)v, lane);
    uint32_t hi = __builtin_amdgcn_readlane((uint32_t)(v >> 32), lane);
    return ((u64)hi << 32) | lo;
}

// ---------------- Stage 1: per-image histogram of score keys (top 12 bits) ----------------
__global__ __launch_bounds__(256) void k_hist(const float4* __restrict__ obj4,
                                              uint32_t* __restrict__ hist) {
    __shared__ uint32_t lh[2][NBIN];   // 32 KiB, 2-way replicated to cut contention
    int b = blockIdx.y;
    for (int i = threadIdx.x; i < NBIN; i += 256) { lh[0][i] = 0; lh[1][i] = 0; }
    __syncthreads();
    const float4* s = obj4 + (size_t)b * NV4;
    int t0 = blockIdx.x * 256 + threadIdx.x;
    uint32_t* h = lh[threadIdx.x & 1];
    float4 v[SCAN_ITER];
#pragma unroll
    for (int k = 0; k < SCAN_ITER; ++k) v[k] = s[t0 + k * SCAN_STRIDE];
#pragma unroll
    for (int k = 0; k < SCAN_ITER; ++k) {
        atomicAdd(&h[fkey(v[k].x) >> 20], 1u);
        atomicAdd(&h[fkey(v[k].y) >> 20], 1u);
        atomicAdd(&h[fkey(v[k].z) >> 20], 1u);
        atomicAdd(&h[fkey(v[k].w) >> 20], 1u);
    }
    __syncthreads();
    uint32_t* gh = hist + (size_t)b * NBIN;
    for (int i = threadIdx.x; i < NBIN; i += 256) {
        uint32_t s2 = lh[0][i] + lh[1][i];
        if (s2) atomicAdd(&gh[i], s2);
    }
}

// ---------------- Stage 2+3 fused: wave 0 computes cutoff bin, then compact ------------
#define LBUF 2048
__global__ __launch_bounds__(256) void k_compact(const float4* __restrict__ obj4,
                                                 const uint32_t* __restrict__ hist,
                                                 uint32_t* __restrict__ cnt,
                                                 u64* __restrict__ cand) {
    __shared__ u64 buf[LBUF];          // 16 KiB
    __shared__ uint32_t lcnt, base, cutsh;
    int b = blockIdx.y;
    if (threadIdx.x == 0) lcnt = 0;
    if (threadIdx.x < 64) {
        int lane = threadIdx.x;
        const uint32_t* h = hist + (size_t)b * NBIN;
        uint32_t gs = 0;
        for (int t = 0; t < 64; ++t) gs += h[lane * 64 + t];
        uint32_t suf = gs;
        for (int d = 1; d < 64; d <<= 1) {
            uint32_t vv = __shfl_down(suf, d);
            if (lane + d < 64) suf += vv;
        }
        unsigned long long m = __ballot(suf >= PRE);
        int G = 63 - __clzll(m);
        uint32_t A = 0;
        if (G < 63) A = __shfl(suf, G + 1);
        uint32_t hv = h[G * 64 + lane];
        uint32_t suf2 = hv;
        for (int d = 1; d < 64; d <<= 1) {
            uint32_t vv = __shfl_down(suf2, d);
            if (lane + d < 64) suf2 += vv;
        }
        unsigned long long m2 = __ballot(A + suf2 >= PRE);
        int t2 = 63 - __clzll(m2);
        if (lane == 0) cutsh = (uint32_t)(G * 64 + t2);
    }
    __syncthreads();
    uint32_t cb = cutsh;
    const float4* s = obj4 + (size_t)b * NV4;
    int t0 = blockIdx.x * 256 + threadIdx.x;
    float4 v[SCAN_ITER];
#pragma unroll
    for (int k = 0; k < SCAN_ITER; ++k) v[k] = s[t0 + k * SCAN_STRIDE];
#pragma unroll
    for (int k = 0; k < SCAN_ITER; ++k) {
        int i4 = (t0 + k * SCAN_STRIDE) * 4;
        float fv[4] = {v[k].x, v[k].y, v[k].z, v[k].w};
#pragma unroll
        for (int c = 0; c < 4; ++c) {
            uint32_t key = fkey(fv[c]);
            if ((key >> 20) >= cb) {
                uint32_t p = atomicAdd(&lcnt, 1u);
                u64 e = ((u64)key << 32) | (uint32_t)(~(uint32_t)(i4 + c));
                if (p < LBUF) buf[p] = e;
                else {
                    uint32_t g = atomicAdd(&cnt[b], 1u);
                    if (g < CAP) cand[(size_t)b * CAP + g] = e;
                }
            }
        }
    }
    __syncthreads();
    uint32_t nb = lcnt < LBUF ? lcnt : LBUF;
    if (threadIdx.x == 0) base = atomicAdd(&cnt[b], nb);
    __syncthreads();
    uint32_t bs = base;
    for (uint32_t t = threadIdx.x; t < nb; t += 256) {
        uint32_t g = bs + t;
        if (g < CAP) cand[(size_t)b * CAP + g] = buf[t];
    }
}

// ---------------- Stage 4+5: counting-rank (readlane broadcast) + decode ----------------
__global__ __launch_bounds__(64) void k_rankdec(const uint32_t* __restrict__ cnt,
                                                const u64* __restrict__ cand,
                                                const float4* __restrict__ anchors,
                                                const float4* __restrict__ deltas,
                                                float4* __restrict__ boxes) {
    int b = blockIdx.x;
    int lane = threadIdx.x;                       // 64
    int slot = blockIdx.y * 64 + lane;            // 0..4095
    uint32_t n = cnt[b]; if (n > CAP) n = CAP;
    const u64* C = cand + (size_t)b * CAP;
    u64 mykey = (slot < (int)n) ? C[slot] : 0ull;
    int ng = ((int)n + 63) >> 6;
    auto ld = [&](int g) -> u64 {
        int j = g * 64 + lane;
        int jc = j < (CAP - 1) ? j : (CAP - 1);
        u64 kv = C[jc];
        return (j < (int)n) ? kv : 0ull;          // 0 never counts (real keys have MSB set)
    };
    u64 kv0 = ld(0), kv1 = ld(1), kv2 = ld(2);
    int r0 = 0, r1 = 0;
    for (int g = 0; g < ng; ++g) {
        u64 kvn = ld(g + 3);
#pragma unroll
        for (int t = 0; t < 64; t += 2) {
            u64 ka = readlane_u64(kv0, t);
            u64 kb = readlane_u64(kv0, t + 1);
            r0 += (ka > mykey) ? 1 : 0;
            r1 += (kb > mykey) ? 1 : 0;
        }
        kv0 = kv1; kv1 = kv2; kv2 = kvn;
    }
    int r = r0 + r1;
    int rank = (slot < (int)n) ? r : slot;        // pads cover rows [n,2048) bijectively
    if (rank < RANKP) {
        float4 outb = make_float4(0.f, 0.f, 0.f, 0.f);
        if (slot < (int)n && rank < PRE) {
            uint32_t idx = ~(uint32_t)mykey;
            if (idx < N) {
                float4 a = anchors[idx];
                float4 d = deltas[(size_t)b * N + idx];
                float w = a.z - a.x, h = a.w - a.y;
                float cx = a.x + 0.5f * w, cy = a.y + 0.5f * h;
                float dw = fminf(d.z, (float)XCLIP);
                float dh = fminf(d.w, (float)XCLIP);
                float pcx = d.x * w + cx, pcy = d.y * h + cy;
                float pw = expf(dw) * w, ph = expf(dh) * h;
                float x1 = pcx - 0.5f * pw, y1 = pcy - 0.5f * ph;
                float x2 = pcx + 0.5f * pw, y2 = pcy + 0.5f * ph;
                x1 = fminf(fmaxf(x1, 0.f), 1024.f);
                y1 = fminf(fmaxf(y1, 0.f), 1024.f);
                x2 = fminf(fmaxf(x2, 0.f), 1024.f);
                y2 = fminf(fmaxf(y2, 0.f), 1024.f);
                outb = make_float4(x1, y1, x2, y2);
            }
        }
        boxes[(size_t)b * RANKP + rank] = outb;
    }
}

// ---------------- Stage 6a: pairwise suppression bitmask + diag + valid ----------------
#define NTRI (NWORD * (NWORD + 1) / 2)   // 528
__global__ void k_mask(const float4* __restrict__ boxes, u64* __restrict__ sup,
                       u64* __restrict__ diagd, u64* __restrict__ valid) {
    int b = blockIdx.x;
    int L = blockIdx.y;
    int ti = 0, rem = L;
    while (rem >= NWORD - ti) { rem -= NWORD - ti; ++ti; }
    int tj = ti + rem;
    __shared__ float4 jb[64];
    __shared__ float ja[64];
    int t = threadIdx.x;  // 64 threads
    const float4* bx = boxes + (size_t)b * RANKP;
    float4 v = bx[tj * 64 + t];
    jb[t] = v;
    ja[t] = (v.z - v.x) * (v.w - v.y);
    int i = ti * 64 + t;
    float4 bi = bx[i];
    float ai = (bi.z - bi.x) * (bi.w - bi.y);
    __syncthreads();
    u64 word = 0;
    for (int jj = 0; jj < 64; ++jj) {
        int j = tj * 64 + jj;
        float4 bj = jb[jj];
        float xx1 = fmaxf(bi.x, bj.x), yy1 = fmaxf(bi.y, bj.y);
        float xx2 = fminf(bi.z, bj.z), yy2 = fminf(bi.w, bj.w);
        float iw = fmaxf(xx2 - xx1, 0.f), ih = fmaxf(yy2 - yy1, 0.f);
        float inter = iw * ih;
        float iou = inter / (ai + ja[jj] - inter);
        if (j > i && iou > NMS_T) word |= 1ull << jj;
    }
    __builtin_nontemporal_store(word, &sup[((size_t)b * RANKP + i) * NWORD + tj]);
    if (ti == tj) {
        __builtin_nontemporal_store(word, &diagd[((size_t)b * NWORD + ti) * 64 + t]);
        bool ok = !((bi.z - bi.x < 1e-3f) || (bi.w - bi.y < 1e-3f));
        u64 bal = __ballot(ok);
        if (t == 0) valid[(size_t)b * NWORD + ti] = bal;
    }
}

// ---------------- Stage 6b+7: chunked greedy NMS, dwordx4 + token-pinned dbuf ----------------
// r17 post-mortem: 33 VMEM/chunk × ~60-90cy service dominates. Now 17 VMEM/chunk via
// dwordx4 (instr i covers rows 4i..4i+3; lane l holds words 2(l&15),2(l&15)+1 of row
// 4i+(l>>4)). The issue asm also defines a TOKEN register; each body begins with
// asm("" : "+v"(remv) : "v"(token)) so the body DATA-DEPENDS on the other buffer's
// issue — regalloc must keep both buffers live (r13/r14: sched_barrier alone failed,
// VGPR=72 proved A/B coalesced; expect ~160 now).
// sup lower-triangle words (w < row's chunk) are NEVER written (0xAA poison from the
// harness) — the `lane >= c` guard keeps them out of remv. Do not remove it.
#define QL16(X) X(0) X(1) X(2) X(3) X(4) X(5) X(6) X(7) X(8) X(9) X(10) X(11) \
    X(12) X(13) X(14) X(15)

#define DECL4A(i) u32x4 A##i;
#define DECL4B(i) u32x4 B##i;
#define ACCA4(i) { uint32_t b4_ = (uint32_t)(kept >> (4 * i));                 \
    uint32_t m_ = 0u - ((b4_ >> j_) & 1u);                                     \
    ael |= A##i.x & m_; aeh |= A##i.y & m_; aol |= A##i.z & m_; aoh |= A##i.w & m_; }
#define ACCB4(i) { uint32_t b4_ = (uint32_t)(kept >> (4 * i));                 \
    uint32_t m_ = 0u - ((b4_ >> j_) & 1u);                                     \
    ael |= B##i.x & m_; aeh |= B##i.y & m_; aol |= B##i.z & m_; aoh |= B##i.w & m_; }

#define ISSUE4(P, CC) do {                                                            \
    const char* p0_ = (const char*)S + ((size_t)((CC) & (NWORD - 1)) << 14);          \
    const char* p1_ = p0_ + 4096;                                                     \
    const char* p2_ = p0_ + 8192;                                                     \
    const char* p3_ = p0_ + 12288;                                                    \
    const char* gd_ = (const char*)Dv + ((size_t)((CC) & (NWORD - 1)) << 9);          \
    asm volatile(                                                                     \
        "global_load_dwordx4 %[q0], %[vo], %[pa] offset:0\n\t"                        \
        "global_load_dwordx4 %[q1], %[vo], %[pa] offset:1024\n\t"                     \
        "global_load_dwordx4 %[q2], %[vo], %[pa] offset:2048\n\t"                     \
        "global_load_dwordx4 %[q3], %[vo], %[pa] offset:3072\n\t"                     \
        "global_load_dwordx4 %[q4], %[vo], %[pb] offset:0\n\t"                        \
        "global_load_dwordx4 %[q5], %[vo], %[pb] offset:1024\n\t"                     \
        "global_load_dwordx4 %[q6], %[vo], %[pb] offset:2048\n\t"                     \
        "global_load_dwordx4 %[q7], %[vo], %[pb] offset:3072\n\t"                     \
        : [q0]"=&v"(P##0), [q1]"=&v"(P##1), [q2]"=&v"(P##2), [q3]"=&v"(P##3),         \
          [q4]"=&v"(P##4), [q5]"=&v"(P##5), [q6]"=&v"(P##6), [q7]"=&v"(P##7)          \
        : [vo]"v"(voff4), [pa]"s"(p0_), [pb]"s"(p1_));                                \
    asm volatile(                                                                     \
        "global_load_dwordx4 %[q8], %[vo], %[pc] offset:0\n\t"                        \
        "global_load_dwordx4 %[q9], %[vo], %[pc] offset:1024\n\t"                     \
        "global_load_dwordx4 %[q10], %[vo], %[pc] offset:2048\n\t"                    \
        "global_load_dwordx4 %[q11], %[vo], %[pc] offset:3072\n\t"                    \
        "global_load_dwordx4 %[q12], %[vo], %[pd] offset:0\n\t"                       \
        "global_load_dwordx4 %[q13], %[vo], %[pd] offset:1024\n\t"                    \
        "global_load_dwordx4 %[q14], %[vo], %[pd] offset:2048\n\t"                    \
        "global_load_dwordx4 %[q15], %[vo], %[pd] offset:3072\n\t"                    \
        "global_load_dwordx2 %[qd], %[vd], %[pe] offset:0\n\t"                        \
        "v_mov_b32 %[tk], 1\n\t"                                                      \
        : [q8]"=&v"(P##8), [q9]"=&v"(P##9), [q10]"=&v"(P##10), [q11]"=&v"(P##11),     \
          [q12]"=&v"(P##12), [q13]"=&v"(P##13), [q14]"=&v"(P##14), [q15]"=&v"(P##15), \
          [qd]"=&v"(P##d), [tk]"=&v"(P##t)                                            \
        : [vo]"v"(voff4), [pc]"s"(p2_), [pd]"s"(p3_),                                 \
          [vd]"v"(vdiag), [pe]"s"(gd_));                                              \
} while (0)

#define WAITV0() do { asm volatile("s_waitcnt vmcnt(0)" ::: "memory");                \
                      __builtin_amdgcn_sched_barrier(0); } while (0)

#define NMS_BODY4(ACCM, DREG, TOK, CC) do {                                           \
    asm volatile("" : "+v"(remv) : "v"(TOK));  /* body data-depends on other issue */ \
    int cc_ = (CC);                                                                   \
    u64 dcur_ = (DREG);                                                               \
    u64 scur = readlane_u64(remv, cc_);                                               \
    _Pragma("unroll") for (int g = 0; g < 4; ++g) {                                   \
        u64 dd[16];                                                                   \
        _Pragma("unroll") for (int i = 0; i < 16; ++i)                                \
            dd[i] = readlane_u64(dcur_, g * 16 + i);                                  \
        _Pragma("unroll") for (int i = 0; i < 16; ++i) {                              \
            int row = g * 16 + i;                                                     \
            if (!((scur >> row) & 1ull)) scur |= dd[i];                               \
        }                                                                             \
    }                                                                                 \
    u64 kept = ~scur;                                                                 \
    uint32_t ael = 0, aeh = 0, aol = 0, aoh = 0;                                      \
    int j_ = lane >> 4;                                                               \
    QL16(ACCM)                                                                        \
    ael |= __shfl_xor(ael, 16); aeh |= __shfl_xor(aeh, 16);                           \
    aol |= __shfl_xor(aol, 16); aoh |= __shfl_xor(aoh, 16);                           \
    ael |= __shfl_xor(ael, 32); aeh |= __shfl_xor(aeh, 32);                           \
    aol |= __shfl_xor(aol, 32); aoh |= __shfl_xor(aoh, 32);                           \
    int src_ = lane >> 1;                                                             \
    uint32_t lel = __shfl(ael, src_), leh = __shfl(aeh, src_);                        \
    uint32_t lol = __shfl(aol, src_), loh = __shfl(aoh, src_);                        \
    u64 wordw = (lane & 1) ? (((u64)loh << 32) | lol) : (((u64)leh << 32) | lel);     \
    if (lane < 32 && lane >= cc_) remv |= wordw;                                      \
    kept_cnt += (int)__popcll(kept);                                                  \
} while (0)

__global__ __launch_bounds__(64, 1) void k_nms(const u64* __restrict__ valid,
                                               const u64* __restrict__ sup,
                                               const u64* __restrict__ diagd,
                                               const float4* __restrict__ boxes,
                                               float4* __restrict__ out) {
    int b = blockIdx.x;
    int lane = threadIdx.x;             // 64
    const u64* S = sup + (size_t)b * RANKP * NWORD;
    const u64* Dv = diagd + (size_t)b * (NWORD * 64);
    uint32_t voff4 = (uint32_t)(lane * 16);
    uint32_t vdiag = (uint32_t)(lane * 8);
    u64 remv = (lane < 32) ? ~valid[(size_t)b * NWORD + lane] : 0ull;
    QL16(DECL4A) u64 Ad; uint32_t At;
    QL16(DECL4B) u64 Bd; uint32_t Bt;
    int kept_cnt = 0;
    ISSUE4(A, 0);
    WAITV0();
    for (int c = 0; c < NWORD; c += 2) {
        ISSUE4(B, c + 1);
        NMS_BODY4(ACCA4, Ad, Bt, c);
        if (kept_cnt >= POST) goto done;
        WAITV0();
        ISSUE4(A, c + 2);
        NMS_BODY4(ACCB4, Bd, At, c + 1);
        if (kept_cnt >= POST) goto done;
        WAITV0();
    }
done: ;
    // ---- epilogue: stable partition (kept first) -> top-1000 gather ----
    int tot = 0;
    for (int ww = 0; ww < NWORD; ++ww)
        tot += (int)__popcll(~readlane_u64(remv, ww));
    u64 below = (1ull << lane) - 1ull;
    int kcum = 0, ucum = 0;
    for (int ww = 0; ww < NWORD; ++ww) {
        u64 kw = ~readlane_u64(remv, ww);
        int pc = (int)__popcll(kw);
        bool kp = (kw >> lane) & 1ull;
        int pos;
        if (kp) pos = kcum + (int)__popcll(kw & below);
        else    pos = tot + ucum + (int)__popcll((~kw) & below);
        if (pos < POST) out[(size_t)b * POST + pos] = boxes[(size_t)b * RANKP + ww * 64 + lane];
        kcum += pc;
        ucum += 64 - pc;
    }
}

extern "C" void kernel_launch(void* const* d_in, const int* in_sizes, int n_in,
                              void* d_out, int out_size, void* d_ws, size_t ws_size,
                              hipStream_t stream) {
    const float* anchors = (const float*)d_in[0];   // [N,4]
    const float* obj     = (const float*)d_in[1];   // [B,N]
    const float* deltas  = (const float*)d_in[2];   // [B,N,4]
    char* ws = (char*)d_ws;

    uint32_t* hist   = (uint32_t*)(ws + 0);        // 131072
    uint32_t* cnt    = (uint32_t*)(ws + 131072);   // 256
    u64*      cand   = (u64*)(ws + 131584);        // B*4096*8 = 262144 -> 393728
    float4*   boxes  = (float4*)(ws + 393728);     // B*2048*16 = 524288 -> 918016
    u64*      valid  = (u64*)(ws + 918016);        // 2048 -> 920064
    u64*      sup    = (u64*)(ws + 920064);        // B*2048*32*8 = 4194304 -> 5114368
    u64*      diagd  = (u64*)(ws + 5114368);       // B*32*64*8 = 131072 -> 5245440

    hipMemsetAsync(ws, 0, 131328, stream);  // hist + cnt

    dim3 gscan(SCAN_BLOCKS, B);
    k_hist<<<gscan, 256, 0, stream>>>((const float4*)obj, hist);
    k_compact<<<gscan, 256, 0, stream>>>((const float4*)obj, hist, cnt, cand);
    dim3 grank(B, CAP / 64);
    k_rankdec<<<grank, 64, 0, stream>>>(cnt, cand, (const float4*)anchors,
                                        (const float4*)deltas, boxes);
    dim3 gmask(B, NTRI);
    k_mask<<<gmask, 64, 0, stream>>>(boxes, sup, diagd, valid);
    k_nms<<<B, 64, 0, stream>>>(valid, sup, diagd, boxes, (float4*)d_out);
}

// Round 20
// 89.041 us; speedup vs baseline: 1.2575x; 1.1943x over previous
//
#include <hip/hip_runtime.h>
#include <stdint.h>

#define B 8
#define N 460800
#define NV4 115200          // N/4 float4 scores per image
#define PRE 2000
#define POST 1000
#define CAP 4096
#define NBIN 4096
#define RANKP 2048
#define NWORD 32
#define NMS_T 0.7f
#define XCLIP 4.135166556742356

#define SCAN_BLOCKS 45      // 45*256*10 = 115200
#define SCAN_ITER 10
#define SCAN_STRIDE (SCAN_BLOCKS * 256)

typedef unsigned long long u64;

__device__ __forceinline__ uint32_t fkey(float f) {
    uint32_t u = __float_as_uint(f);
    return (u & 0x80000000u) ? ~u : (u | 0x80000000u);
}

__device__ __forceinline__ u64 readlane_u64(u64 v, int lane) {
    uint32_t lo = __builtin_amdgcn_readlane((uint32_t)v, lane);
    uint32_t hi = __builtin_amdgcn_readlane((uint32_t)(v >> 32), lane);
    return ((u64)hi << 32) | lo;
}

// ---------------- Stage 1: per-image histogram of score keys (top 12 bits) ----------------
__global__ __launch_bounds__(256) void k_hist(const float4* __restrict__ obj4,
                                              uint32_t* __restrict__ hist) {
    __shared__ uint32_t lh[2][NBIN];   // 32 KiB, 2-way replicated to cut contention
    int b = blockIdx.y;
    for (int i = threadIdx.x; i < NBIN; i += 256) { lh[0][i] = 0; lh[1][i] = 0; }
    __syncthreads();
    const float4* s = obj4 + (size_t)b * NV4;
    int t0 = blockIdx.x * 256 + threadIdx.x;
    uint32_t* h = lh[threadIdx.x & 1];
    float4 v[SCAN_ITER];
#pragma unroll
    for (int k = 0; k < SCAN_ITER; ++k) v[k] = s[t0 + k * SCAN_STRIDE];
#pragma unroll
    for (int k = 0; k < SCAN_ITER; ++k) {
        atomicAdd(&h[fkey(v[k].x) >> 20], 1u);
        atomicAdd(&h[fkey(v[k].y) >> 20], 1u);
        atomicAdd(&h[fkey(v[k].z) >> 20], 1u);
        atomicAdd(&h[fkey(v[k].w) >> 20], 1u);
    }
    __syncthreads();
    uint32_t* gh = hist + (size_t)b * NBIN;
    for (int i = threadIdx.x; i < NBIN; i += 256) {
        uint32_t s2 = lh[0][i] + lh[1][i];
        if (s2) atomicAdd(&gh[i], s2);
    }
}

// ---------------- Stage 2+3 fused: wave 0 computes cutoff bin, then compact ------------
#define LBUF 2048
__global__ __launch_bounds__(256) void k_compact(const float4* __restrict__ obj4,
                                                 const uint32_t* __restrict__ hist,
                                                 uint32_t* __restrict__ cnt,
                                                 u64* __restrict__ cand) {
    __shared__ u64 buf[LBUF];          // 16 KiB
    __shared__ uint32_t lcnt, base, cutsh;
    int b = blockIdx.y;
    if (threadIdx.x == 0) lcnt = 0;
    if (threadIdx.x < 64) {
        int lane = threadIdx.x;
        const uint32_t* h = hist + (size_t)b * NBIN;
        uint32_t gs = 0;
        for (int t = 0; t < 64; ++t) gs += h[lane * 64 + t];
        uint32_t suf = gs;
        for (int d = 1; d < 64; d <<= 1) {
            uint32_t vv = __shfl_down(suf, d);
            if (lane + d < 64) suf += vv;
        }
        unsigned long long m = __ballot(suf >= PRE);
        int G = 63 - __clzll(m);
        uint32_t A = 0;
        if (G < 63) A = __shfl(suf, G + 1);
        uint32_t hv = h[G * 64 + lane];
        uint32_t suf2 = hv;
        for (int d = 1; d < 64; d <<= 1) {
            uint32_t vv = __shfl_down(suf2, d);
            if (lane + d < 64) suf2 += vv;
        }
        unsigned long long m2 = __ballot(A + suf2 >= PRE);
        int t2 = 63 - __clzll(m2);
        if (lane == 0) cutsh = (uint32_t)(G * 64 + t2);
    }
    __syncthreads();
    uint32_t cb = cutsh;
    const float4* s = obj4 + (size_t)b * NV4;
    int t0 = blockIdx.x * 256 + threadIdx.x;
    float4 v[SCAN_ITER];
#pragma unroll
    for (int k = 0; k < SCAN_ITER; ++k) v[k] = s[t0 + k * SCAN_STRIDE];
#pragma unroll
    for (int k = 0; k < SCAN_ITER; ++k) {
        int i4 = (t0 + k * SCAN_STRIDE) * 4;
        float fv[4] = {v[k].x, v[k].y, v[k].z, v[k].w};
#pragma unroll
        for (int c = 0; c < 4; ++c) {
            uint32_t key = fkey(fv[c]);
            if ((key >> 20) >= cb) {
                uint32_t p = atomicAdd(&lcnt, 1u);
                u64 e = ((u64)key << 32) | (uint32_t)(~(uint32_t)(i4 + c));
                if (p < LBUF) buf[p] = e;
                else {
                    uint32_t g = atomicAdd(&cnt[b], 1u);
                    if (g < CAP) cand[(size_t)b * CAP + g] = e;
                }
            }
        }
    }
    __syncthreads();
    uint32_t nb = lcnt < LBUF ? lcnt : LBUF;
    if (threadIdx.x == 0) base = atomicAdd(&cnt[b], nb);
    __syncthreads();
    uint32_t bs = base;
    for (uint32_t t = threadIdx.x; t < nb; t += 256) {
        uint32_t g = bs + t;
        if (g < CAP) cand[(size_t)b * CAP + g] = buf[t];
    }
}

// ---------------- Stage 4+5: counting-rank (readlane broadcast) + decode ----------------
__global__ __launch_bounds__(64) void k_rankdec(const uint32_t* __restrict__ cnt,
                                                const u64* __restrict__ cand,
                                                const float4* __restrict__ anchors,
                                                const float4* __restrict__ deltas,
                                                float4* __restrict__ boxes) {
    int b = blockIdx.x;
    int lane = threadIdx.x;                       // 64
    int slot = blockIdx.y * 64 + lane;            // 0..4095
    uint32_t n = cnt[b]; if (n > CAP) n = CAP;
    const u64* C = cand + (size_t)b * CAP;
    u64 mykey = (slot < (int)n) ? C[slot] : 0ull;
    int ng = ((int)n + 63) >> 6;
    auto ld = [&](int g) -> u64 {
        int j = g * 64 + lane;
        int jc = j < (CAP - 1) ? j : (CAP - 1);
        u64 kv = C[jc];
        return (j < (int)n) ? kv : 0ull;          // 0 never counts (real keys have MSB set)
    };
    u64 kv0 = ld(0), kv1 = ld(1), kv2 = ld(2);
    int r0 = 0, r1 = 0;
    for (int g = 0; g < ng; ++g) {
        u64 kvn = ld(g + 3);
#pragma unroll
        for (int t = 0; t < 64; t += 2) {
            u64 ka = readlane_u64(kv0, t);
            u64 kb = readlane_u64(kv0, t + 1);
            r0 += (ka > mykey) ? 1 : 0;
            r1 += (kb > mykey) ? 1 : 0;
        }
        kv0 = kv1; kv1 = kv2; kv2 = kvn;
    }
    int r = r0 + r1;
    int rank = (slot < (int)n) ? r : slot;        // pads cover rows [n,2048) bijectively
    if (rank < RANKP) {
        float4 outb = make_float4(0.f, 0.f, 0.f, 0.f);
        if (slot < (int)n && rank < PRE) {
            uint32_t idx = ~(uint32_t)mykey;
            if (idx < N) {
                float4 a = anchors[idx];
                float4 d = deltas[(size_t)b * N + idx];
                float w = a.z - a.x, h = a.w - a.y;
                float cx = a.x + 0.5f * w, cy = a.y + 0.5f * h;
                float dw = fminf(d.z, (float)XCLIP);
                float dh = fminf(d.w, (float)XCLIP);
                float pcx = d.x * w + cx, pcy = d.y * h + cy;
                float pw = expf(dw) * w, ph = expf(dh) * h;
                float x1 = pcx - 0.5f * pw, y1 = pcy - 0.5f * ph;
                float x2 = pcx + 0.5f * pw, y2 = pcy + 0.5f * ph;
                x1 = fminf(fmaxf(x1, 0.f), 1024.f);
                y1 = fminf(fmaxf(y1, 0.f), 1024.f);
                x2 = fminf(fmaxf(x2, 0.f), 1024.f);
                y2 = fminf(fmaxf(y2, 0.f), 1024.f);
                outb = make_float4(x1, y1, x2, y2);
            }
        }
        boxes[(size_t)b * RANKP + rank] = outb;
    }
}

// ---------------- Stage 6a: ADJACENCY bitmask + occupancy + valid ----------------
// adj[i][w] bit k: IoU(i, 64w+k) > T AND 64w+k < i  (lower triangle: "i is suppressible
// by earlier box j"). IoU is numerically symmetric, so this is the exact transpose of
// the old sup matrix. occ[i] bit w set iff adj[i][w] != 0 (rare; via atomicOr on a
// zeroed buffer). Only words w <= i/64 are ever WRITTEN — but occ guards all reads.
// r19 BUG FIX: the diagonal branch wrote valid[b][0] from EVERY diagonal block
// (stray `valid[...+t]` with t==0) — a 32-way race on word 0. Only valid[b][tr] here.
#define NTRI (NWORD * (NWORD + 1) / 2)   // 528
__global__ void k_mask(const float4* __restrict__ boxes, u64* __restrict__ adj,
                       uint32_t* __restrict__ occ, u64* __restrict__ valid) {
    int b = blockIdx.x;
    int L = blockIdx.y;
    int tw = 0, rem = L;
    while (rem >= NWORD - tw) { rem -= NWORD - tw; ++tw; }
    int tr = tw + rem;                   // tw <= tr: columns = earlier tile, rows = later
    __shared__ float4 jb[64];
    __shared__ float ja[64];
    int t = threadIdx.x;  // 64 threads
    const float4* bx = boxes + (size_t)b * RANKP;
    float4 v = bx[tw * 64 + t];
    jb[t] = v;
    ja[t] = (v.z - v.x) * (v.w - v.y);
    int i = tr * 64 + t;                 // this lane's row (later box)
    float4 bi = bx[i];
    float ai = (bi.z - bi.x) * (bi.w - bi.y);
    __syncthreads();
    u64 word = 0;
    for (int kk = 0; kk < 64; ++kk) {
        int j = tw * 64 + kk;
        float4 bj = jb[kk];
        float xx1 = fmaxf(bi.x, bj.x), yy1 = fmaxf(bi.y, bj.y);
        float xx2 = fminf(bi.z, bj.z), yy2 = fminf(bi.w, bj.w);
        float iw = fmaxf(xx2 - xx1, 0.f), ih = fmaxf(yy2 - yy1, 0.f);
        float inter = iw * ih;
        float iou = inter / (ai + ja[kk] - inter);   // NaN -> compare false
        if (j < i && iou > NMS_T) word |= 1ull << kk;
    }
    __builtin_nontemporal_store(word, &adj[((size_t)b * RANKP + i) * NWORD + tw]);
    if (word) atomicOr(&occ[(size_t)b * RANKP + i], 1u << tw);
    if (tw == tr) {
        bool ok = !((bi.z - bi.x < 1e-3f) || (bi.w - bi.y < 1e-3f));
        u64 bal = __ballot(ok);
        if (t == 0) valid[(size_t)b * NWORD + tr] = bal;
    }
}

// ---------------- Stage 6b+7: sparse greedy NMS + stable-partition output ----------------
// kept[i] = valid[i] && no kept j<i with IoU>T. Per 64-chunk: om = ballot(occ!=0);
// if om==0 (common): keptword = validword in O(1). Sparse rows resolved via readlane
// against prefetched first-adj-words (t1[], 32 regs, one latency) + rare global
// fallback for rows with >=2 occupied word-groups. No memory waits in the chain.
// Early exit once kept_cnt >= POST (output positions < POST then final; unprocessed
// chunks keep keptword = validword, consistent with the partition epilogue).
__global__ __launch_bounds__(64, 1) void k_nms(const u64* __restrict__ valid,
                                               const u64* __restrict__ adj,
                                               const uint32_t* __restrict__ occ,
                                               const float4* __restrict__ boxes,
                                               float4* __restrict__ out) {
    int b = blockIdx.x;
    int lane = threadIdx.x;             // 64
    const u64* AdjG = adj + (size_t)b * RANKP * NWORD;
    const uint32_t* OccG = occ + (size_t)b * RANKP;
    // per-lane occ: o[g] = occ[g*64 + lane]   (32 independent coalesced loads)
    uint32_t o[NWORD];
#pragma unroll
    for (int g = 0; g < NWORD; ++g) o[g] = OccG[g * 64 + lane];
    u64 vw = (lane < 32) ? valid[(size_t)b * NWORD + lane] : 0ull;
    // prefetch first nonzero adj word per row (unused lanes read word 0 — always written)
    u64 t1[NWORD];
#pragma unroll
    for (int g = 0; g < NWORD; ++g) {
        uint32_t m = o[g];
        int w1 = m ? (int)__builtin_ctz(m) : 0;
        t1[g] = AdjG[(size_t)(g * 64 + lane) * NWORD + w1];
    }
    u64 kw = vw;                        // lane w holds kept-word w; init = valid (final
                                        // value for chunks never processed)
    int kcnt = 0;
    bool done = false;
#pragma unroll
    for (int c = 0; c < NWORD; ++c) {
        if (!done) {
            u64 om = __ballot(o[c] != 0);           // rows in this chunk with suppressors
            u64 vmask = readlane_u64(vw, c);
            u64 kc;
            if (om == 0ull) {
                kc = vmask;                          // O(1) common case
            } else {
                kc = vmask & ~om;                    // undecided rows cleared
                u64 mm = om;
                while (mm) {
                    int i = (int)__builtin_ctzll(mm); mm &= mm - 1;
                    uint32_t occv = __builtin_amdgcn_readlane(o[c], i);
                    bool suppressed = false;
                    uint32_t m2 = occv;
                    int w = (int)__builtin_ctz(m2); m2 &= m2 - 1;
                    u64 arow = readlane_u64(t1[c], i);
                    u64 ks = (w == c) ? kc : readlane_u64(kw, w);
                    if (arow & ks) suppressed = true;
                    while (m2 && !suppressed) {      // rare: >=2 occupied word-groups
                        w = (int)__builtin_ctz(m2); m2 &= m2 - 1;
                        u64 a2 = AdjG[(size_t)(c * 64 + i) * NWORD + w];
                        ks = (w == c) ? kc : readlane_u64(kw, w);
                        if (a2 & ks) suppressed = true;
                    }
                    if (((vmask >> i) & 1ull) && !suppressed) kc |= 1ull << i;
                }
            }
            if (lane == c) kw = kc;
            kcnt += (int)__popcll(kc);
            if (kcnt >= POST) done = true;
        }
    }
    // ---- epilogue: stable partition (kept first) -> top-1000 gather ----
    int tot = 0;
    for (int ww = 0; ww < NWORD; ++ww)
        tot += (int)__popcll(readlane_u64(kw, ww));
    u64 below = (1ull << lane) - 1ull;
    int kcum = 0, ucum = 0;
    for (int ww = 0; ww < NWORD; ++ww) {
        u64 kv = readlane_u64(kw, ww);
        int pc = (int)__popcll(kv);
        bool kp = (kv >> lane) & 1ull;
        int pos;
        if (kp) pos = kcum + (int)__popcll(kv & below);
        else    pos = tot + ucum + (int)__popcll((~kv) & below);
        if (pos < POST) out[(size_t)b * POST + pos] = boxes[(size_t)b * RANKP + ww * 64 + lane];
        kcum += pc;
        ucum += 64 - pc;
    }
}

extern "C" void kernel_launch(void* const* d_in, const int* in_sizes, int n_in,
                              void* d_out, int out_size, void* d_ws, size_t ws_size,
                              hipStream_t stream) {
    const float* anchors = (const float*)d_in[0];   // [N,4]
    const float* obj     = (const float*)d_in[1];   // [B,N]
    const float* deltas  = (const float*)d_in[2];   // [B,N,4]
    char* ws = (char*)d_ws;

    uint32_t* hist   = (uint32_t*)(ws + 0);        // 131072
    uint32_t* cnt    = (uint32_t*)(ws + 131072);   // 256
    uint32_t* occ    = (uint32_t*)(ws + 131328);   // B*2048*4 = 65536 -> 196864
    u64*      cand   = (u64*)(ws + 196864);        // B*4096*8 = 262144 -> 459008
    float4*   boxes  = (float4*)(ws + 459008);     // B*2048*16 = 524288 -> 983296
    u64*      valid  = (u64*)(ws + 983296);        // 2048 -> 985344
    u64*      adj    = (u64*)(ws + 985344);        // B*2048*32*8 = 4194304 -> 5179648

    hipMemsetAsync(ws, 0, 196864, stream);  // hist + cnt + occ

    dim3 gscan(SCAN_BLOCKS, B);
    k_hist<<<gscan, 256, 0, stream>>>((const float4*)obj, hist);
    k_compact<<<gscan, 256, 0, stream>>>((const float4*)obj, hist, cnt, cand);
    dim3 grank(B, CAP / 64);
    k_rankdec<<<grank, 64, 0, stream>>>(cnt, cand, (const float4*)anchors,
                                        (const float4*)deltas, boxes);
    dim3 gmask(B, NTRI);
    k_mask<<<gmask, 64, 0, stream>>>(boxes, adj, occ, valid);
    k_nms<<<B, 64, 0, stream>>>(valid, adj, occ, boxes, (float4*)d_out);
}